// Round 4
// baseline (510.437 us; speedup 1.0000x reference)
//
#include <hip/hip_runtime.h>

// y = x @ block_diag(M repeated), g = 128.
// Flattened: Y[R,128] = X[R,128] * M[128,128], R = numel(x)/128.
// Memory-bound GEMM: bf16 MFMA (fp32 accumulate) to get compute off the
// critical path; fp32 VALU would be slower than the HBM floor.

typedef float f32x4 __attribute__((ext_vector_type(4)));
typedef short s16x8 __attribute__((ext_vector_type(8)));

#define GSZ   128
#define PITCH 136   // 128 + 8 bf16 pad: 272B row pitch -> bank stride 4, ~2-way (free)

// fp32 -> bf16 round-to-nearest-even
static __device__ __forceinline__ unsigned short f2bf(float f) {
  union { float f; unsigned int u; } v; v.f = f;
  unsigned int u = v.u;
  unsigned int r = (u + 0x7fffu + ((u >> 16) & 1u)) >> 16;
  return (unsigned short)r;
}

__global__ __launch_bounds__(256, 4)
void ff_block_gemm(const float* __restrict__ X, const float* __restrict__ M,
                   float* __restrict__ Y, int ntiles) {
  // MT[c][k] = bf16(M[k][c])  (transposed so B-fragment reads are k-contiguous)
  __shared__ unsigned short MT[GSZ * PITCH];

  const int tid = threadIdx.x;
  #pragma unroll 4
  for (int it = 0; it < 64; ++it) {
    int idx = it * 256 + tid;        // coalesced read of M
    int k = idx >> 7;
    int c = idx & 127;
    MT[c * PITCH + k] = f2bf(M[idx]);
  }
  __syncthreads();

  const int w  = tid >> 6;   // wave 0..3
  const int l  = tid & 63;
  const int lr = l & 15;     // A-row within 16 / D-col within 16
  const int kg = l >> 4;     // k-group 0..3 (8 contiguous k each)

  for (int t = blockIdx.x; t < ntiles; t += gridDim.x) {
    const int r0 = t * 64 + w * 16;                       // this wave's 16 rows
    const float* xp = X + (size_t)(r0 + lr) * GSZ + kg * 8;

    // A fragments: row = lane&15, k = 8*(lane>>4) + i, k-step stride 32
    s16x8 a[4];
    #pragma unroll
    for (int ks = 0; ks < 4; ++ks) {
      f32x4 f0 = *(const f32x4*)(xp + ks * 32);
      f32x4 f1 = *(const f32x4*)(xp + ks * 32 + 4);
      s16x8 av;
      av[0] = (short)f2bf(f0[0]); av[1] = (short)f2bf(f0[1]);
      av[2] = (short)f2bf(f0[2]); av[3] = (short)f2bf(f0[3]);
      av[4] = (short)f2bf(f1[0]); av[5] = (short)f2bf(f1[1]);
      av[6] = (short)f2bf(f1[2]); av[7] = (short)f2bf(f1[3]);
      a[ks] = av;
    }

    f32x4 acc[8];
    #pragma unroll
    for (int nt = 0; nt < 8; ++nt) acc[nt] = (f32x4){0.f, 0.f, 0.f, 0.f};

    #pragma unroll
    for (int ks = 0; ks < 4; ++ks) {
      #pragma unroll
      for (int nt = 0; nt < 8; ++nt) {
        // B fragment: col = lane&15, k = 8*(lane>>4) + i  -> MT[col][k..k+7]
        const s16x8 b = *(const s16x8*)&MT[(nt * 16 + lr) * PITCH + ks * 32 + kg * 8];
        acc[nt] = __builtin_amdgcn_mfma_f32_16x16x32_bf16(a[ks], b, acc[nt], 0, 0, 0);
      }
    }

    // D layout (verified m89/m91): col = lane&15, row = (lane>>4)*4 + reg
    float* yp = Y + (size_t)(r0 + kg * 4) * GSZ + lr;
    #pragma unroll
    for (int nt = 0; nt < 8; ++nt) {
      #pragma unroll
      for (int q = 0; q < 4; ++q) {
        yp[q * GSZ + nt * 16] = acc[nt][q];
      }
    }
  }
}

extern "C" void kernel_launch(void* const* d_in, const int* in_sizes, int n_in,
                              void* d_out, int out_size, void* d_ws, size_t ws_size,
                              hipStream_t stream) {
  const float* X = (const float*)d_in[0];
  const float* M = (const float*)d_in[1];
  float* Y = (float*)d_out;
  const int R = in_sizes[0] / GSZ;       // 524288 rows
  const int ntiles = R / 64;             // 64 rows per block-iteration
  int grid = ntiles < 1024 ? ntiles : 1024;  // 4 blocks/CU (LDS-limited), persistent
  hipLaunchKernelGGL(ff_block_gemm, dim3(grid), dim3(256), 0, stream,
                     X, M, Y, ntiles);
}